// Round 1
// baseline (3947.043 us; speedup 1.0000x reference)
//
#include <hip/hip_runtime.h>
#include <math.h>

#define NR 8192      // NA == NT
#define DIM 256
#define NBLK 512     // fused-kernel blocks == column-partial chunks (2 per CU)
#define CROWS 16     // rows per chunk
#define NSUB 16      // sub-chunks per chunk (1 row each, double-buffered)
// 10 * log2(e): converts distances directly into base-2 log domain
#define SCALE2 14.426950408889634f

typedef unsigned short ushort_t;
typedef __attribute__((ext_vector_type(8))) short bfrag;   // 8 bf16 (4 VGPRs)
typedef __attribute__((ext_vector_type(4))) float facc;    // 4 fp32 acc

// v_exp_f32 / v_log_f32 are base-2 natively — use them raw
__device__ __forceinline__ float fexp2(float x) {
#if __has_builtin(__builtin_amdgcn_exp2f)
    return __builtin_amdgcn_exp2f(x);
#else
    return exp2f(x);
#endif
}
__device__ __forceinline__ float flog2(float x) {
#if __has_builtin(__builtin_amdgcn_logf)
    return __builtin_amdgcn_logf(x);
#else
    return log2f(x);
#endif
}

// async global->LDS copy, 16 B per lane, no transit VGPRs.
__device__ __forceinline__ void gl2lds16(const float* gp, float* lp) {
#if __has_builtin(__builtin_amdgcn_global_load_lds)
    __builtin_amdgcn_global_load_lds(
        (const __attribute__((address_space(1))) unsigned int*)gp,
        (__attribute__((address_space(3))) unsigned int*)lp, 16, 0, 0);
#else
    *(float4*)lp = *(const float4*)gp;   // fallback: callers pass lane-adjusted ptrs
#endif
}

// raw waits/barrier: barrier WITHOUT vmcnt(0) drain; counted vmcnt gates.
__device__ __forceinline__ void wait_vm0()  { asm volatile("s_waitcnt vmcnt(0)" ::: "memory"); }
__device__ __forceinline__ void wait_vm4()  { asm volatile("s_waitcnt vmcnt(4)" ::: "memory"); }
__device__ __forceinline__ void bar_lgkm()  { asm volatile("s_waitcnt lgkmcnt(0)\ns_barrier" ::: "memory"); }

// base-2 online LSE combine
__device__ __forceinline__ void lse_comb2(float& m, float& s, float mo, float so) {
    float nm = fmaxf(m, mo);
    s = s * fexp2(m - nm) + so * fexp2(mo - nm);
    m = nm;
}

// grouped-4 online LSE update (1 tree-max + 1 correction exp per 4 values)
__device__ __forceinline__ void lse_upd4(float& m, float& s,
                                         float v0, float v1, float v2, float v3) {
    float m4 = fmaxf(fmaxf(v0, v1), fmaxf(v2, v3));
    float nm = fmaxf(m, m4);
    float e = fexp2(v0 - nm) + fexp2(v1 - nm) + fexp2(v2 - nm) + fexp2(v3 - nm);
    s = fmaf(s, fexp2(m - nm), e);
    m = nm;
}

// single-value online LSE update
__device__ __forceinline__ void lse_upd1(float& m, float& s, float v) {
    float nm = fmaxf(m, v);
    s = fmaf(s, fexp2(m - nm), fexp2(v - nm));
    m = nm;
}

// RNE float -> bf16 bits (manual: deterministic, no API variance)
__device__ __forceinline__ ushort_t f2bf(float x) {
    unsigned u = __float_as_uint(x);
    u += 0x7FFFu + ((u >> 16) & 1u);
    return (ushort_t)(u >> 16);
}
__device__ __forceinline__ float bf2f(ushort_t b) {
    return __uint_as_float(((unsigned)b) << 16);
}

// ---------------- init ----------------
__global__ void init_zero(float* __restrict__ g) {
    int t = blockIdx.x * 256 + threadIdx.x;
    if (t < NR) g[t] = 0.0f;
}

// ---------------- out[M,DIM] = A[M,DIM] @ W[DIM,DIM] + bias ----------------
__global__ __launch_bounds__(256) void gemm_qk(const float* __restrict__ A,
                                               const float* __restrict__ W,
                                               const float* __restrict__ bias,
                                               float* __restrict__ out) {
    __shared__ float As[16][68];
    __shared__ float Ws[16][68];
    const int t  = threadIdx.x;
    const int r0 = blockIdx.x * 64;
    const int c0 = blockIdx.y * 64;
    const int ty = t >> 4, tx = t & 15;
    const int arow = t >> 2;
    const int ak   = (t & 3) * 4;
    const int wrow = t >> 4;
    const int wcol = (t & 15) * 4;
    float acc[4][4] = {};
    for (int k0 = 0; k0 < DIM; k0 += 16) {
        float4 av = *(const float4*)(A + (size_t)(r0 + arow) * DIM + k0 + ak);
        float4 wv = *(const float4*)(W + (size_t)(k0 + wrow) * DIM + c0 + wcol);
        __syncthreads();
        As[ak + 0][arow] = av.x; As[ak + 1][arow] = av.y;
        As[ak + 2][arow] = av.z; As[ak + 3][arow] = av.w;
        *(float4*)&Ws[wrow][wcol] = wv;
        __syncthreads();
#pragma unroll
        for (int kk = 0; kk < 16; ++kk) {
            float4 a = *(const float4*)&As[kk][ty * 4];
            float4 b = *(const float4*)&Ws[kk][tx * 4];
            float aa[4] = {a.x, a.y, a.z, a.w};
            float bb[4] = {b.x, b.y, b.z, b.w};
#pragma unroll
            for (int i = 0; i < 4; ++i)
#pragma unroll
                for (int j = 0; j < 4; ++j)
                    acc[i][j] = fmaf(aa[i], bb[j], acc[i][j]);
        }
    }
#pragma unroll
    for (int i = 0; i < 4; ++i) {
        float4 o;
        o.x = acc[i][0] + bias[c0 + tx * 4 + 0];
        o.y = acc[i][1] + bias[c0 + tx * 4 + 1];
        o.z = acc[i][2] + bias[c0 + tx * 4 + 2];
        o.w = acc[i][3] + bias[c0 + tx * 4 + 3];
        *(float4*)(out + (size_t)(r0 + ty * 4 + i) * DIM + c0 + tx * 4) = o;
    }
}

// ---------------- row squared norms ----------------
__global__ __launch_bounds__(64) void row_norm(const float* __restrict__ x,
                                               float* __restrict__ out) {
    const int row = blockIdx.x, lane = threadIdx.x;
    float4 v = *(const float4*)(x + (size_t)row * DIM + lane * 4);
    float s = v.x * v.x + v.y * v.y + v.z * v.z + v.w * v.w;
#pragma unroll
    for (int off = 32; off > 0; off >>= 1) s += __shfl_xor(s, off);
    if (lane == 0) out[row] = s;
}

// ---------------- split fp32 -> bf16 hi + bf16 lo (lo = bf16(x - hi)) ----------------
__global__ __launch_bounds__(256) void split_bf16(const float* __restrict__ x,
                                                  ushort_t* __restrict__ hi,
                                                  ushort_t* __restrict__ lo) {
    const int idx = (blockIdx.x * 256 + threadIdx.x) * 4;
    float4 v = *(const float4*)(x + idx);
    ushort_t h0 = f2bf(v.x), h1 = f2bf(v.y), h2 = f2bf(v.z), h3 = f2bf(v.w);
    ushort4 hv = make_ushort4(h0, h1, h2, h3);
    ushort4 lv = make_ushort4(f2bf(v.x - bf2f(h0)), f2bf(v.y - bf2f(h1)),
                              f2bf(v.z - bf2f(h2)), f2bf(v.w - bf2f(h3)));
    *(ushort4*)(hi + idx) = hv;
    *(ushort4*)(lo + idx) = lv;
}

// ---------------- S = SCALE2*(qn_i + kn_j - 2*q_i.k_j) via split-bf16 MFMA ----------
// 4096 blocks x 256 threads (4 waves, 2x2 of 64x64). mfma_f32_16x16x32_bf16:
// A[m=lane&15][k=quad*8+j], B[n=lane&15][k=quad*8+j] -> contiguous 16 B/lane loads
// straight from global (row-major bf16, L2/L3-served). Full 4-product split
// (hh+hl+lh+ll): per-element error <= 2^-19 — adds ~4e-4 exponent error,
// negligible vs the ~1e-2 LSE accumulation error. C/D: col=lane&15,
// row=quad*4+reg (m89-verified).
__global__ __launch_bounds__(256) void dist_mfma(const ushort_t* __restrict__ qh,
                                                 const ushort_t* __restrict__ ql,
                                                 const ushort_t* __restrict__ kh,
                                                 const ushort_t* __restrict__ kl,
                                                 const float* __restrict__ qn,
                                                 const float* __restrict__ kn,
                                                 float* __restrict__ S) {
    const int t = threadIdx.x;
    const int wv = t >> 6, lane = t & 63;
    const int r0 = blockIdx.y * 128 + (wv >> 1) * 64;
    const int c0 = blockIdx.x * 128 + (wv & 1) * 64;
    const int fr = lane & 15;       // row (A) / col (B) within 16x16 tile
    const int fq = lane >> 4;       // quad -> k-subrange / C-row group
    facc acc[4][4];
#pragma unroll
    for (int i = 0; i < 4; ++i)
#pragma unroll
        for (int j = 0; j < 4; ++j) acc[i][j] = (facc){0.f, 0.f, 0.f, 0.f};

    for (int k0 = 0; k0 < DIM; k0 += 32) {
        const int ks = k0 + fq * 8;
        bfrag ah[4], al[4], bh[4], bl[4];
#pragma unroll
        for (int mi = 0; mi < 4; ++mi) {
            const size_t ao = (size_t)(r0 + mi * 16 + fr) * DIM + ks;
            ah[mi] = *(const bfrag*)(qh + ao);
            al[mi] = *(const bfrag*)(ql + ao);
        }
#pragma unroll
        for (int ni = 0; ni < 4; ++ni) {
            const size_t bo = (size_t)(c0 + ni * 16 + fr) * DIM + ks;
            bh[ni] = *(const bfrag*)(kh + bo);
            bl[ni] = *(const bfrag*)(kl + bo);
        }
#pragma unroll
        for (int mi = 0; mi < 4; ++mi)
#pragma unroll
            for (int ni = 0; ni < 4; ++ni) {
                acc[mi][ni] = __builtin_amdgcn_mfma_f32_16x16x32_bf16(ah[mi], bh[ni], acc[mi][ni], 0, 0, 0);
                acc[mi][ni] = __builtin_amdgcn_mfma_f32_16x16x32_bf16(ah[mi], bl[ni], acc[mi][ni], 0, 0, 0);
                acc[mi][ni] = __builtin_amdgcn_mfma_f32_16x16x32_bf16(al[mi], bh[ni], acc[mi][ni], 0, 0, 0);
                acc[mi][ni] = __builtin_amdgcn_mfma_f32_16x16x32_bf16(al[mi], bl[ni], acc[mi][ni], 0, 0, 0);
            }
    }
    // epilogue: S[row][col] = (qn + kn - 2*dot) * SCALE2
#pragma unroll
    for (int mi = 0; mi < 4; ++mi) {
        float qnr[4];
#pragma unroll
        for (int r = 0; r < 4; ++r) qnr[r] = qn[r0 + mi * 16 + fq * 4 + r];
#pragma unroll
        for (int ni = 0; ni < 4; ++ni) {
            const int col = c0 + ni * 16 + fr;
            const float knc = kn[col];
#pragma unroll
            for (int r = 0; r < 4; ++r) {
                const int row = r0 + mi * 16 + fq * 4 + r;
                S[(size_t)row * NR + col] = (qnr[r] + knc - 2.0f * acc[mi][ni][r]) * SCALE2;
            }
        }
    }
}

// ---------------- MLP logits: relu(A@W1+b1)@W2 + b2 ----------------
__global__ __launch_bounds__(128) void mlp_logits(const float* __restrict__ A,
                                                  const float* __restrict__ W1,
                                                  const float* __restrict__ b1,
                                                  const float* __restrict__ W2,
                                                  const float* __restrict__ b2,
                                                  float* __restrict__ logits) {
    __shared__ float ar[DIM];
    __shared__ float red[2];
    const int t = threadIdx.x;
    const int row = blockIdx.x;
    *(float2*)&ar[t * 2] = *(const float2*)(A + (size_t)row * DIM + t * 2);
    __syncthreads();
    float h = b1[t];
#pragma unroll 8
    for (int kk = 0; kk < DIM; ++kk) h = fmaf(ar[kk], W1[kk * 128 + t], h);
    float val = fmaxf(h, 0.0f) * W2[t];
#pragma unroll
    for (int off = 32; off > 0; off >>= 1) val += __shfl_xor(val, off);
    if ((t & 63) == 0) red[t >> 6] = val;
    __syncthreads();
    if (t == 0) logits[row] = red[0] + red[1] + b2[0];
}

// ---------------- softmax over 8192 logits -> log2(b + 1e-20) ----------------
__global__ __launch_bounds__(1024) void softmax_logb(const float* __restrict__ logits,
                                                     float* __restrict__ logb2) {
    __shared__ float redm[16], reds[16];
    const int t = threadIdx.x;
    float l[8];
    float m = -INFINITY;
#pragma unroll
    for (int i = 0; i < 8; ++i) { l[i] = logits[i * 1024 + t]; m = fmaxf(m, l[i]); }
#pragma unroll
    for (int off = 32; off > 0; off >>= 1) m = fmaxf(m, __shfl_xor(m, off));
    if ((t & 63) == 0) redm[t >> 6] = m;
    __syncthreads();
    if (t < 64) {
        float v = (t < 16) ? redm[t] : -INFINITY;
#pragma unroll
        for (int off = 8; off > 0; off >>= 1) v = fmaxf(v, __shfl_xor(v, off));
        if (t == 0) redm[0] = v;
    }
    __syncthreads();
    m = redm[0];
    float s = 0.0f;
#pragma unroll
    for (int i = 0; i < 8; ++i) s += __expf(l[i] - m);
#pragma unroll
    for (int off = 32; off > 0; off >>= 1) s += __shfl_xor(s, off);
    if ((t & 63) == 0) reds[t >> 6] = s;
    __syncthreads();
    if (t < 64) {
        float v = (t < 16) ? reds[t] : 0.0f;
#pragma unroll
        for (int off = 8; off > 0; off >>= 1) v += __shfl_xor(v, off);
        if (t == 0) reds[0] = v;
    }
    __syncthreads();
    s = reds[0];
    float invs = 1.0f / s;
#pragma unroll
    for (int i = 0; i < 8; ++i)
        logb2[i * 1024 + t] = log2f(__expf(l[i] - m) * invs + 1e-20f);
}

// ---------------- fused iteration: row-granular DOUBLE-BUFFERED DMA staging -------
// Per sub-chunk (1 row = 32 KB): wait vmcnt(4) [own wave's 4 loads of row sc
// landed; row sc+1's 4 loads stay IN FLIGHT across both barriers] -> row-LSE
// (each wave owns a 1024-col segment) -> barrier A -> combine -> column update
// over full row -> barrier B -> issue DMA(sc+2) into the buffer just freed.
// vmcnt never drains to 0 mid-loop (T3/T4). To keep the per-wave vmcnt count
// exact, NO global accesses occur inside the loop: logb2 is staged to LDS in
// the prologue, f values are stashed in a register and stored after the loop.
__global__ __launch_bounds__(512, 4) void iter_fused(const float* __restrict__ S,
                                                     const float* __restrict__ g,
                                                     const float* __restrict__ logb2,
                                                     float* __restrict__ f,
                                                     float* __restrict__ pm) {
    __shared__ float buf[2][NR];        // 2 x 32 KB double-buffered row staging
    __shared__ float redm[8], reds[8];
    __shared__ float lbsh[CROWS];
    const int t = threadIdx.x;
    const int wv = t >> 6, lane = t & 63;
    const int chunk = blockIdx.x;
    const int r0 = chunk * CROWS;
    const int seg = wv * 1024;          // this wave's 1/8-row segment
    const int loff = lane * 4;

    // stage logb2 for this chunk's rows (done FIRST: compiler drains its own
    // vmcnt before the ds_write, so the loop's counted waits stay exact)
    if (t < CROWS) lbsh[t] = logb2[r0 + t];

    // preload this wave's g segment (constant within one launch): 4 float4
    float4 greg[4];
#pragma unroll
    for (int it = 0; it < 4; ++it)
        greg[it] = *(const float4*)(g + seg + it * 256 + loff);

    // column accumulators: thread t owns cols {j*2048 + t*4 + c}
    float cm[4][4], cs[4][4];
#pragma unroll
    for (int j = 0; j < 4; ++j)
#pragma unroll
        for (int c = 0; c < 4; ++c) { cm[j][c] = -INFINITY; cs[j][c] = 0.0f; }

    // prologue: DMA rows 0 and 1 (4 loads each per wave -> 8 outstanding + 4 greg)
    {
        const float* S0 = S + (size_t)(r0 + 0) * NR + seg;
        const float* S1 = S + (size_t)(r0 + 1) * NR + seg;
#pragma unroll
        for (int it = 0; it < 4; ++it)
#if __has_builtin(__builtin_amdgcn_global_load_lds)
            gl2lds16(S0 + it * 256 + loff, &buf[0][seg + it * 256]);
#else
            gl2lds16(S0 + it * 256 + loff, &buf[0][seg + it * 256 + loff]);
#endif
#pragma unroll
        for (int it = 0; it < 4; ++it)
#if __has_builtin(__builtin_amdgcn_global_load_lds)
            gl2lds16(S1 + it * 256 + loff, &buf[1][seg + it * 256]);
#else
            gl2lds16(S1 + it * 256 + loff, &buf[1][seg + it * 256 + loff]);
#endif
    }

    float fmine = 0.0f;
    for (int sc = 0; sc < NSUB; ++sc) {
        const int p = sc & 1;
        // vmcnt ledger (per wave): steady state = 8 outstanding (rows sc, sc+1).
        // wait(4): row sc's 4 loads (+greg on sc==0) retired; row sc+1 in flight.
        if (sc < NSUB - 1) wait_vm4(); else wait_vm0();

        // ---- phase 1: row-LSE over this wave's own (self-DMA'd) segment ----
        float m = -INFINITY, s = 0.0f;
#pragma unroll
        for (int it = 0; it < 4; ++it) {
            float4 v = *(const float4*)&buf[p][seg + it * 256 + loff];
            float4 gv = greg[it];
            lse_upd4(m, s, v.x + gv.x, v.y + gv.y, v.z + gv.z, v.w + gv.w);
        }
#pragma unroll
        for (int off = 32; off > 0; off >>= 1) {
            float mo = __shfl_xor(m, off);
            float so = __shfl_xor(s, off);
            lse_comb2(m, s, mo, so);
        }
        if (lane == 0) { redm[wv] = m; reds[wv] = s; }
        bar_lgkm();   // barrier A: every wave's DMA(sc) landed; redm/reds visible

        // ---- all threads: tree-combine 8 wave partials -> f for this row ----
        float m0 = redm[0], s0 = reds[0];
        lse_comb2(m0, s0, redm[1], reds[1]);
        float m2 = redm[2], s2 = reds[2];
        lse_comb2(m2, s2, redm[3], reds[3]);
        float m4 = redm[4], s4 = reds[4];
        lse_comb2(m4, s4, redm[5], reds[5]);
        float m6 = redm[6], s6 = reds[6];
        lse_comb2(m6, s6, redm[7], reds[7]);
        lse_comb2(m0, s0, m2, s2);
        lse_comb2(m4, s4, m6, s6);
        lse_comb2(m0, s0, m4, s4);
        const float fr = lbsh[sc] - (m0 + flog2(s0));
        if (t == sc) fmine = fr;            // row index == sc (1 row/sub-chunk)

        // ---- phase 2: column partial-LSE over the staged row ----
#pragma unroll
        for (int j = 0; j < 4; ++j) {
            const int c = j * 2048 + t * 4;
            float4 a = *(const float4*)&buf[p][c];
            lse_upd1(cm[j][0], cs[j][0], a.x + fr);
            lse_upd1(cm[j][1], cs[j][1], a.y + fr);
            lse_upd1(cm[j][2], cs[j][2], a.z + fr);
            lse_upd1(cm[j][3], cs[j][3], a.w + fr);
        }
        bar_lgkm();   // barrier B: whole block done reading buf[p]

        // ---- refill the freed buffer with row sc+2 (stays in flight) ----
        if (sc + 2 < NSUB) {
            const float* Sn = S + (size_t)(r0 + sc + 2) * NR + seg;
#pragma unroll
            for (int it = 0; it < 4; ++it)
#if __has_builtin(__builtin_amdgcn_global_load_lds)
                gl2lds16(Sn + it * 256 + loff, &buf[p][seg + it * 256]);
#else
                gl2lds16(Sn + it * 256 + loff, &buf[p][seg + it * 256 + loff]);
#endif
        }
    }
    if (t < CROWS) f[r0 + t] = fmine;

    // write column partials for this chunk as a single float L = m + log2(s)
#pragma unroll
    for (int j = 0; j < 4; ++j) {
        float4 L;
        L.x = cm[j][0] + flog2(cs[j][0]);
        L.y = cm[j][1] + flog2(cs[j][1]);
        L.z = cm[j][2] + flog2(cs[j][2]);
        L.w = cm[j][3] + flog2(cs[j][3]);
        *(float4*)&pm[(size_t)chunk * NR + j * 2048 + t * 4] = L;
    }
}

// ---------------- combine partials -> g (256 blocks, two-level LSE) ----------------
__global__ __launch_bounds__(256) void col_combine(const float* __restrict__ pm,
                                                   float* __restrict__ g,
                                                   float log_a2) {
    __shared__ float Lsh[8][32];
    const int cl = threadIdx.x & 31;       // column within block
    const int gp = threadIdx.x >> 5;       // chunk group (0..7), 64 chunks each
    const int col = blockIdx.x * 32 + cl;
    float m = -INFINITY, s = 0.0f;
#pragma unroll
    for (int ch = gp * 64; ch < gp * 64 + 64; ch += 4) {
        float l0 = pm[(size_t)(ch + 0) * NR + col];
        float l1 = pm[(size_t)(ch + 1) * NR + col];
        float l2 = pm[(size_t)(ch + 2) * NR + col];
        float l3 = pm[(size_t)(ch + 3) * NR + col];
        lse_upd4(m, s, l0, l1, l2, l3);
    }
    Lsh[gp][cl] = m + flog2(s);
    __syncthreads();
    if (gp == 0) {
        float mm = -INFINITY, ss = 0.0f;
        lse_upd4(mm, ss, Lsh[0][cl], Lsh[1][cl], Lsh[2][cl], Lsh[3][cl]);
        lse_upd4(mm, ss, Lsh[4][cl], Lsh[5][cl], Lsh[6][cl], Lsh[7][cl]);
        g[col] = log_a2 - (mm + flog2(ss));
    }
}

// ---------------- T = exp2(f + S + g), in place; global sum == 1 analytically ------
// note: no __restrict__ on S/out — they alias (in-place)
__global__ __launch_bounds__(256) void write_pass(const float* S,
                                                  const float* __restrict__ f,
                                                  const float* __restrict__ g,
                                                  float* out) {
    const int wv = threadIdx.x >> 6, lane = threadIdx.x & 63;
    const int row = blockIdx.x * 4 + wv;
    const float fi = f[row];
    const float4* Sr = (const float4*)(S + (size_t)row * NR);
    const float4* gr = (const float4*)g;
    float4* Or = (float4*)(out + (size_t)row * NR);
#pragma unroll 4
    for (int it = 0; it < NR / 256; ++it) {
        const int idx = it * 64 + lane;
        float4 sv = Sr[idx];
        float4 gv = gr[idx];
        float4 o;
        o.x = fexp2(fi + sv.x + gv.x);
        o.y = fexp2(fi + sv.y + gv.y);
        o.z = fexp2(fi + sv.z + gv.z);
        o.w = fexp2(fi + sv.w + gv.w);
        Or[idx] = o;
    }
}

extern "C" void kernel_launch(void* const* d_in, const int* in_sizes, int n_in,
                              void* d_out, int out_size, void* d_ws, size_t ws_size,
                              hipStream_t stream) {
    (void)in_sizes; (void)n_in; (void)out_size; (void)ws_size;
    const float* A  = (const float*)d_in[0];
    const float* Tk = (const float*)d_in[1];
    const float* Wq = (const float*)d_in[2];
    const float* bq = (const float*)d_in[3];
    const float* Wk = (const float*)d_in[4];
    const float* bk = (const float*)d_in[5];
    const float* W1 = (const float*)d_in[6];
    const float* b1 = (const float*)d_in[7];
    const float* W2 = (const float*)d_in[8];
    const float* b2 = (const float*)d_in[9];
    float* S  = (float*)d_out;           // 8192x8192 base-2 log_K lives in d_out
    float* ws = (float*)d_ws;
    float* qn     = ws; ws += NR;
    float* kn     = ws; ws += NR;
    float* logb2  = ws; ws += NR;
    float* logits = ws; ws += NR;
    float* f      = ws; ws += NR;
    float* g      = ws; ws += NR;
    float* pm     = ws; ws += (size_t)NBLK * NR;   // 16 MB
    float* q      = ws; ws += (size_t)NR * DIM;    // 8 MB
    float* k      = ws; ws += (size_t)NR * DIM;    // 8 MB
    // bf16 split arrays overlay pm (16.78 MB == 4 x NR*DIM ushorts): they are
    // dead once dist_mfma finishes, before the first iter_fused writes pm.
    ushort_t* qh = (ushort_t*)pm;
    ushort_t* ql = qh + (size_t)NR * DIM;
    ushort_t* kh = ql + (size_t)NR * DIM;
    ushort_t* kl = kh + (size_t)NR * DIM;

    const float log_a2 = -13.0f; // log2(1/8192 + 1e-20)

    init_zero<<<32, 256, 0, stream>>>(g);
    gemm_qk<<<dim3(128, 4), 256, 0, stream>>>(A, Wq, bq, q);
    gemm_qk<<<dim3(128, 4), 256, 0, stream>>>(Tk, Wk, bk, k);
    row_norm<<<NR, 64, 0, stream>>>(q, qn);
    row_norm<<<NR, 64, 0, stream>>>(k, kn);
    split_bf16<<<NR * DIM / 1024, 256, 0, stream>>>(q, qh, ql);
    split_bf16<<<NR * DIM / 1024, 256, 0, stream>>>(k, kh, kl);
    mlp_logits<<<NR, 128, 0, stream>>>(A, W1, b1, W2, b2, logits);
    softmax_logb<<<1, 1024, 0, stream>>>(logits, logb2);
    dist_mfma<<<dim3(64, 64), 256, 0, stream>>>(qh, ql, kh, kl, qn, kn, S);
    for (int it = 0; it < 50; ++it) {
        iter_fused<<<NBLK, 512, 0, stream>>>(S, g, logb2, f, pm);
        col_combine<<<NR / 32, 256, 0, stream>>>(pm, g, log_a2);
    }
    write_pass<<<NR / 4, 256, 0, stream>>>(S, f, g, S);
}